// Round 1
// baseline (25.291 us; speedup 1.0000x reference)
//
#include <hip/hip_runtime.h>

// XTermFrequency: per-row histogram over VOCAB bins, normalized by row sum.
// One workgroup per row; LDS histogram processed in NCHUNK vocab chunks so the
// fp32 histogram fits in LDS (VOCAB*4B = 201KB > 160KB LDS).
#define VOCAB 50257
#define NCHUNK 4
#define CHUNK ((VOCAB + NCHUNK - 1) / NCHUNK)  // 12565 bins -> 50260 B LDS

__global__ __launch_bounds__(1024) void XTermFrequency_5471788335935_kernel(
    const int* __restrict__ asg, const float* __restrict__ w,
    float* __restrict__ out, int S)
{
    __shared__ float hist[CHUNK];
    __shared__ float s_sum;
    __shared__ float s_inv;

    const int b   = blockIdx.x;
    const int tid = threadIdx.x;
    const long long rowoff = (long long)b * S;
    const int*   __restrict__ row  = asg + rowoff;
    const float* __restrict__ wrow = w   + rowoff;
    float*       __restrict__ orow = out + (long long)b * VOCAB;

    // Cache this thread's samples in registers when S == 2*blockDim (the bench
    // shape: S=2048, block=1024). Generic fallback re-reads global (L1-resident).
    const bool cached = ((S & 1) == 0) && ((S >> 1) == (int)blockDim.x);
    int2   ra = make_int2(0, 0);
    float2 rw = make_float2(0.f, 0.f);
    float  ws = 0.f;
    if (cached) {
        ra = reinterpret_cast<const int2*>(row)[tid];
        rw = reinterpret_cast<const float2*>(wrow)[tid];
        ws = rw.x + rw.y;
    } else {
        for (int s = tid; s < S; s += blockDim.x) ws += wrow[s];
    }

    if (tid == 0) s_sum = 0.f;
    __syncthreads();
    // wave(64)-level reduce, then one LDS atomic per wave
    #pragma unroll
    for (int off = 32; off > 0; off >>= 1) ws += __shfl_down(ws, off, 64);
    if ((tid & 63) == 0) atomicAdd(&s_sum, ws);
    __syncthreads();
    if (tid == 0) s_inv = 1.0f / s_sum;
    // s_inv becomes visible to all threads at the barrier inside the first
    // chunk iteration (after the zero loop), before anyone reads it.

    for (int c = 0; c < NCHUNK; ++c) {
        const int lo = c * CHUNK;

        for (int i = tid; i < CHUNK; i += blockDim.x) hist[i] = 0.f;
        __syncthreads();

        if (cached) {
            const int v0 = ra.x - lo;
            const int v1 = ra.y - lo;
            if ((unsigned)v0 < (unsigned)CHUNK) atomicAdd(&hist[v0], rw.x);
            if ((unsigned)v1 < (unsigned)CHUNK) atomicAdd(&hist[v1], rw.y);
        } else {
            for (int s = tid; s < S; s += blockDim.x) {
                const int v = row[s] - lo;
                if ((unsigned)v < (unsigned)CHUNK) atomicAdd(&hist[v], wrow[s]);
            }
        }
        __syncthreads();

        const float inv = s_inv;
        const int hi = min(CHUNK, VOCAB - lo);
        for (int i = tid; i < hi; i += blockDim.x) orow[lo + i] = hist[i] * inv;
        __syncthreads();  // hist reused next chunk
    }
}

extern "C" void kernel_launch(void* const* d_in, const int* in_sizes, int n_in,
                              void* d_out, int out_size, void* d_ws, size_t ws_size,
                              hipStream_t stream) {
    const int*   asg = (const int*)d_in[0];
    const float* w   = (const float*)d_in[1];
    float*       out = (float*)d_out;

    const int B = out_size / VOCAB;          // 512
    const int S = in_sizes[0] / B;           // 2048

    XTermFrequency_5471788335935_kernel<<<B, 1024, 0, stream>>>(asg, w, out, S);
}

// Round 2
// 23.775 us; speedup vs baseline: 1.0638x; 1.0638x over previous
//
#include <hip/hip_runtime.h>

// XTermFrequency: per-row histogram over VOCAB bins, normalized by row sum.
// One workgroup per row; LDS histogram processed in NCHUNK vocab chunks so the
// fp32 histogram fits in LDS (VOCAB*4B = 201KB > 160KB LDS).
//
// Key optimization vs v1: inter-chunk barriers use lgkmcnt(0)-only s_barrier
// (LDS ordering), NOT __syncthreads() — hipcc's __syncthreads drains vmcnt(0),
// which serialized each chunk's 50KB of global stores against the next chunk's
// LDS work. With the relaxed barrier, stores stay in flight across chunks.
#define VOCAB 50257
#define NCHUNK 4
#define CHUNK ((VOCAB + NCHUNK - 1) / NCHUNK)  // 12565 bins -> 50260 B LDS

// Workgroup barrier that waits only on LDS ops (lgkmcnt), leaving global
// stores in flight. Safe here: no thread ever reads global data written by
// another thread; barriers only protect the shared LDS histogram.
#define LDS_BARRIER()                                            \
    do {                                                         \
        asm volatile("s_waitcnt lgkmcnt(0)" ::: "memory");       \
        __builtin_amdgcn_s_barrier();                            \
        __builtin_amdgcn_sched_barrier(0);                       \
    } while (0)

__global__ __launch_bounds__(1024) void XTermFrequency_5471788335935_kernel(
    const int* __restrict__ asg, const float* __restrict__ w,
    float* __restrict__ out, int S)
{
    __shared__ float hist[CHUNK];
    __shared__ float s_sum;
    __shared__ float s_inv;

    const int b   = blockIdx.x;
    const int tid = threadIdx.x;
    const long long rowoff = (long long)b * S;
    const int*   __restrict__ row  = asg + rowoff;
    const float* __restrict__ wrow = w   + rowoff;
    float*       __restrict__ orow = out + (long long)b * VOCAB;

    // Cache this thread's samples in registers when S == 2*blockDim (the bench
    // shape: S=2048, block=1024). Generic fallback re-reads global (L1/L2-hot).
    const bool cached = ((S & 1) == 0) && ((S >> 1) == (int)blockDim.x);
    int2   ra = make_int2(0, 0);
    float2 rw = make_float2(0.f, 0.f);
    float  ws = 0.f;
    if (cached) {
        ra = reinterpret_cast<const int2*>(row)[tid];
        rw = reinterpret_cast<const float2*>(wrow)[tid];
        ws = rw.x + rw.y;
    } else {
        for (int s = tid; s < S; s += blockDim.x) ws += wrow[s];
    }

    if (tid == 0) s_sum = 0.f;
    __syncthreads();
    // wave(64)-level reduce, then one LDS atomic per wave
    #pragma unroll
    for (int off = 32; off > 0; off >>= 1) ws += __shfl_down(ws, off, 64);
    if ((tid & 63) == 0) atomicAdd(&s_sum, ws);
    __syncthreads();
    if (tid == 0) s_inv = 1.0f / s_sum;

    // Zero the histogram once; after that, the store loop re-zeros the bins
    // it reads, so no separate zero phase per chunk.
    for (int i = tid; i < CHUNK; i += blockDim.x) hist[i] = 0.f;
    LDS_BARRIER();   // also publishes s_inv

    const float inv = s_inv;

    // Stagger chunk order across blocks so the grid's HBM store bursts spread
    // over different phases instead of convoying.
    const int phase = b & (NCHUNK - 1);

    for (int cc = 0; cc < NCHUNK; ++cc) {
        const int c  = (cc + phase) & (NCHUNK - 1);
        const int lo = c * CHUNK;

        // scatter into LDS histogram
        if (cached) {
            const int v0 = ra.x - lo;
            const int v1 = ra.y - lo;
            if ((unsigned)v0 < (unsigned)CHUNK) atomicAdd(&hist[v0], rw.x);
            if ((unsigned)v1 < (unsigned)CHUNK) atomicAdd(&hist[v1], rw.y);
        } else {
            for (int s = tid; s < S; s += blockDim.x) {
                const int v = row[s] - lo;
                if ((unsigned)v < (unsigned)CHUNK) atomicAdd(&hist[v], wrow[s]);
            }
        }
        LDS_BARRIER();

        // stream out normalized counts; re-zero each bin for the next chunk.
        const int hi = min(CHUNK, VOCAB - lo);
        for (int i = tid; i < hi; i += blockDim.x) {
            const float h = hist[i];
            hist[i] = 0.f;
            orow[lo + i] = h * inv;
        }
        LDS_BARRIER();  // zeros visible before next chunk's scatter
    }
}

extern "C" void kernel_launch(void* const* d_in, const int* in_sizes, int n_in,
                              void* d_out, int out_size, void* d_ws, size_t ws_size,
                              hipStream_t stream) {
    const int*   asg = (const int*)d_in[0];
    const float* w   = (const float*)d_in[1];
    float*       out = (float*)d_out;

    const int B = out_size / VOCAB;          // 512
    const int S = in_sizes[0] / B;           // 2048

    XTermFrequency_5471788335935_kernel<<<B, 1024, 0, stream>>>(asg, w, out, S);
}